// Round 19
// baseline (67.959 us; speedup 1.0000x reference)
//
#include <hip/hip_runtime.h>

#define C_CURV   0.01f
#define SQRT_C   0.1f
#define EPS_W    1e-6f
#define MIN_NORM 1e-10f
#define BALL_EPS 1e-5f
#define CAP      32    // bucket row = 128B; P(deg>=32 | Poisson(8)) ~ 1e-11

typedef __attribute__((ext_vector_type(4))) float f32x4;

__device__ __forceinline__ float fast_rcp(float x)   { return __builtin_amdgcn_rcpf(x); }
__device__ __forceinline__ float fast_sqrt(float x)  { return __builtin_amdgcn_sqrtf(x); }
__device__ __forceinline__ float fast_rsqrt(float x) { return __builtin_amdgcn_rsqf(x); }
__device__ __forceinline__ float tanh_over_x(float x) {   // tanh(x)/x, x>0
    float t = __expf(2.0f * x);
    return (t - 1.0f) * fast_rcp((t + 1.0f) * x);
}
__device__ __forceinline__ unsigned bf16_rne(float x) {
    unsigned u = __float_as_uint(x);
    return (u + 0x7FFFu + ((u >> 16) & 1u)) >> 16;
}
__device__ __forceinline__ float group4_sum(float v) {   // sum over aligned 4-lane quad
    v += __shfl_xor(v, 1, 64);
    v += __shfl_xor(v, 2, 64);
    return v;
}

// K0: zero cursor[N] AND pack rel_weight f32 -> bf16x2 global (wpack).
__global__ __launch_bounds__(256) void fhnn_zero_pack(
        int* __restrict__ cursor, int n4,
        const float* __restrict__ rel_weight,
        unsigned* __restrict__ wpack,    // [R*128] u32 = bf16x2
        int nPack) {                     // = R*64 (each item packs one f32x4 -> uint2)
    int i = blockIdx.x * blockDim.x + threadIdx.x;
    if (i < n4) ((int4*)cursor)[i] = make_int4(0, 0, 0, 0);
    int p = i - n4;
    if (p >= 0 && p < nPack) {
        f32x4 w = ((const f32x4*)rel_weight)[p];
        uint2 o;
        o.x = bf16_rne(w.x) | (bf16_rne(w.y) << 16);
        o.y = bf16_rne(w.z) | (bf16_rne(w.w) << 16);
        ((uint2*)wpack)[p] = o;
    }
}

// K1 (fused, disjoint block ranges): node pre-pass (4 lanes/node) + edge scatter.
__global__ __launch_bounds__(256) void fhnn_prepscatter(
        const float* __restrict__ h_hyper,
        const float* __restrict__ loop_weight,
        const int*   __restrict__ src,
        const int*   __restrict__ dst,
        const int*   __restrict__ etype,
        float* __restrict__ h_tan,
        float* __restrict__ loop_hyp,
        float* __restrict__ ynorm,       // [N]: |loop_hyp|^2 precomputed
        int*      __restrict__ cursor,
        unsigned* __restrict__ bucket,   // [N][CAP], word = src | etype<<16
        int N, int E, int blocksN) {
    if ((int)blockIdx.x >= blocksN) {
        int e = (blockIdx.x - blocksN) * blockDim.x + threadIdx.x;
        if (e >= E) return;
        int t = dst[e];
        int slot = atomicAdd(&cursor[t], 1);
        if (slot < CAP)
            bucket[(size_t)t * CAP + slot] = (unsigned)src[e] | ((unsigned)etype[e] << 16);
        return;
    }
    __shared__ float Wl[256];
    Wl[threadIdx.x] = loop_weight[threadIdx.x];
    __syncthreads();

    int gid = blockIdx.x * blockDim.x + threadIdx.x;
    int t = gid >> 2, j = gid & 3;
    if (t >= N) return;

    f32x4 x = ((const f32x4*)h_hyper)[gid];

    float sq  = group4_sum(x.x * x.x + x.y * x.y + x.z * x.z + x.w * x.w);
    float n   = fast_sqrt(fmaxf(sq, MIN_NORM));
    float scn = SQRT_C * n;
    float z   = fminf(scn, 1.0f - BALL_EPS);
    float at  = 0.5f * __logf((1.0f + z) * fast_rcp(1.0f - z));   // arctanh
    float s   = at * fast_rcp(scn);
    f32x4 ht  = x * s;
    ((f32x4*)h_tan)[gid] = ht;

    f32x4 acc = (f32x4)(0.0f);
    #pragma unroll
    for (int q = 0; q < 4; ++q) {
        float h0 = __shfl(ht.x, q, 4);
        float h1 = __shfl(ht.y, q, 4);
        float h2 = __shfl(ht.z, q, 4);
        float h3 = __shfl(ht.w, q, 4);
        const f32x4* Wrow = (const f32x4*)Wl;
        acc += h0 * Wrow[(4 * q + 0) * 4 + j];
        acc += h1 * Wrow[(4 * q + 1) * 4 + j];
        acc += h2 * Wrow[(4 * q + 2) * 4 + j];
        acc += h3 * Wrow[(4 * q + 3) * 4 + j];
    }
    float sq2 = group4_sum(acc.x * acc.x + acc.y * acc.y + acc.z * acc.z + acc.w * acc.w);
    float n2  = fast_sqrt(fmaxf(sq2, MIN_NORM));
    float f2  = tanh_over_x(SQRT_C * n2);           // exp_map_zero factor
    ((f32x4*)loop_hyp)[gid] = acc * f2;
    if (j == 0) ynorm[t] = sq2 * f2 * f2;           // |loop_hyp|^2 for reduce epilogue
}

// WSTEP: one uint2 (= 4 bf16 = W[row][4j..4j+3]) from GLOBAL wpack + unpack + fma.
// WSP is uint2*, I is ALREADY in uint2 units (4*row).   [R17 bug: had +2*I]
#define WSTEP(HS, I, WSP) { \
    uint2 w = *((WSP) + (I)); \
    f32x4 wvv; \
    wvv.x = __uint_as_float(w.x << 16); \
    wvv.y = __uint_as_float(w.x & 0xFFFF0000u); \
    wvv.z = __uint_as_float(w.y << 16); \
    wvv.w = __uint_as_float(w.y & 0xFFFF0000u); \
    a4 += (HS) * wvv; }

#define EDGE(H0, H1, H2, H3, RR, VALID) { \
    const uint2* Ws = (const uint2*)(wpack + (size_t)(RR) * 128) + (unsigned)j; \
    f32x4 a4 = (f32x4)(0.0f); \
    WSTEP((H0).x,  0, Ws) WSTEP((H0).y,  4, Ws) WSTEP((H0).z,  8, Ws) WSTEP((H0).w, 12, Ws) \
    WSTEP((H1).x, 16, Ws) WSTEP((H1).y, 20, Ws) WSTEP((H1).z, 24, Ws) WSTEP((H1).w, 28, Ws) \
    WSTEP((H2).x, 32, Ws) WSTEP((H2).y, 36, Ws) WSTEP((H2).z, 40, Ws) WSTEP((H2).w, 44, Ws) \
    WSTEP((H3).x, 48, Ws) WSTEP((H3).y, 52, Ws) WSTEP((H3).z, 56, Ws) WSTEP((H3).w, 60, Ws) \
    f32x4 v = a4 + *(const f32x4*)(rel_emb + (size_t)(RR) * 16 + 4 * j); \
    float sq = group4_sum(v.x * v.x + v.y * v.y + v.z * v.z + v.w * v.w); \
    float f  = tanh_over_x(SQRT_C * fast_sqrt(fmaxf(sq, MIN_NORM))); \
    float m2 = f * f * sq; \
    float lam = 2.0f * fast_rcp(1.0f - C_CURV * m2 + EPS_W); \
    float cf = (VALID) ? (f * lam) : 0.0f; \
    accM += v * cf; \
    accL += (VALID) ? lam : 0.0f; }

// Edge-block: decode pk, gather h row, run EDGE. k-index = slot + 4*blk.
#define EDGEBLK(PK, KIDX) { \
    bool vld = (KIDX) < cn; \
    int s = vld ? (int)((PK) & 0xFFFFu) : 0; \
    int r = vld ? (int)((PK) >> 16) : 0; \
    const f32x4* H = (const f32x4*)(h_tan + (size_t)s * 16); \
    f32x4 q0 = H[0], q1 = H[1], q2 = H[2], q3 = H[3]; \
    EDGE(q0, q1, q2, q3, r, vld) }

// K2: reduce, NO LDS -> 256-thr blocks, occupancy limited only by VGPR.
// W read as bf16x2 pairs from global wpack (118 KB, L1/L2-resident).
// Strided slot->k map with wave-uniform __any skips; cursor/pk prefetch.
__global__ __launch_bounds__(256) void fhnn_reduce(
        const float*    __restrict__ h_tan,
        const unsigned* __restrict__ wpack,
        const float*    __restrict__ rel_emb,
        const unsigned* __restrict__ bucket,
        const int*      __restrict__ cursor,
        const float*    __restrict__ node_norm,
        const float*    __restrict__ loop_hyp,
        const float*    __restrict__ ynorm,
        float*          __restrict__ out,
        int N) {
    int wid  = (blockIdx.x * blockDim.x + threadIdx.x) >> 6;   // global wave
    int lane = threadIdx.x & 63;
    int grp  = lane >> 4;
    int slot = (lane >> 2) & 3;
    int j    = lane & 3;
    int wstart  = wid * 4 + grp;
    int nstride = (gridDim.x * blockDim.x >> 6) * 4;

    // prime: first node-group's cursor + first bucket word
    int cnF = 0;
    unsigned pk0 = 0u;
    if (wstart < N) {
        cnF = cursor[wstart];
        pk0 = bucket[(size_t)wstart * CAP + slot];
    }

    for (int t = wstart; t < N; t += nstride) {
        int tn = t + nstride;
        int cnF_n = 0;
        unsigned pk0_n = 0u;
        if (tn < N) {
            cnF_n = cursor[tn];
            pk0_n = bucket[(size_t)tn * CAP + slot];
        }

        int cnFull = cnF;
        int cn = min(cnFull, CAP);
        size_t bbase = (size_t)t * CAP + slot;

        unsigned pk1 = bucket[bbase + 4];
        unsigned pk2 = bucket[bbase + 8];
        unsigned pk3 = bucket[bbase + 12];

        float en = node_norm[t];
        f32x4 y  = ((const f32x4*)(loop_hyp + (size_t)t * 16))[j];
        float y2 = ynorm[t];

        f32x4 accM = (f32x4)(0.0f);
        float accL = 0.0f;

        EDGEBLK(pk0, slot)
        if (__any(cn >  4)) EDGEBLK(pk1, slot + 4)
        if (__any(cn >  8)) EDGEBLK(pk2, slot + 8)
        if (__any(cn > 12)) EDGEBLK(pk3, slot + 12)
        if (__any(cn > 16)) {                                  // rare tail (~0.3%)
            for (int k = 16 + slot; k < cn; k += 4) {
                unsigned pk = bucket[(size_t)t * CAP + k];
                int s = (int)(pk & 0xFFFFu);
                int r = (int)(pk >> 16);
                const f32x4* H = (const f32x4*)(h_tan + (size_t)s * 16);
                f32x4 q0 = H[0], q1 = H[1], q2 = H[2], q3 = H[3];
                EDGE(q0, q1, q2, q3, r, true)
            }
        }

        #pragma unroll
        for (int m = 4; m <= 8; m <<= 1) {
            accM.x += __shfl_xor(accM.x, m, 64);
            accM.y += __shfl_xor(accM.y, m, 64);
            accM.z += __shfl_xor(accM.z, m, 64);
            accM.w += __shfl_xor(accM.w, m, 64);
            accL   += __shfl_xor(accL,   m, 64);
        }

        float wsc   = en * fast_rcp((float)cnFull * en + EPS_W);  // norm_sum = deg*en
        float denom = wsc * accL + EPS_W;
        float rs    = wsc * fast_rcp(denom);
        f32x4 x     = accM * rs;

        float x2 = group4_sum(x.x * x.x + x.y * x.y + x.z * x.z + x.w * x.w);
        const float maxn  = (1.0f - BALL_EPS) / SQRT_C;
        const float maxn2 = maxn * maxn;
        bool over = (x2 > maxn2);
        float scale = over ? (maxn * fast_rsqrt(x2)) : 1.0f;
        x *= scale;
        float x2p = over ? maxn2 : x2;

        float xy = group4_sum(x.x * y.x + x.y * y.y + x.z * y.z + x.w * y.w);

        float a1  = 1.0f + 2.0f * C_CURV * xy + C_CURV * y2;
        float b1  = 1.0f - C_CURV * x2p;
        f32x4 num = a1 * x + b1 * y;
        float d2  = 1.0f + 2.0f * C_CURV * xy + C_CURV * C_CURV * x2p * y2;
        if (slot == 0)
            ((f32x4*)out)[t * 4 + j] = num * fast_rcp(fmaxf(d2, MIN_NORM));

        cnF = cnF_n;
        pk0 = pk0_n;
    }
}

extern "C" void kernel_launch(void* const* d_in, const int* in_sizes, int n_in,
                              void* d_out, int out_size, void* d_ws, size_t ws_size,
                              hipStream_t stream) {
    const float* h_hyper     = (const float*)d_in[0];
    const float* node_norm   = (const float*)d_in[1];
    const float* rel_weight  = (const float*)d_in[2];
    const float* loop_weight = (const float*)d_in[3];
    const float* rel_emb     = (const float*)d_in[4];
    const int*   src         = (const int*)d_in[5];
    const int*   dst         = (const int*)d_in[6];
    const int*   etype       = (const int*)d_in[7];

    const int N = in_sizes[1];          // node_norm is [N,1]
    const int E = in_sizes[5];
    const int R = in_sizes[2] / 256;    // rel_weight is [R,16,16]

    char* ws = (char*)d_ws;
    size_t offs = 0;
    auto alloc = [&](size_t bytes) -> void* {
        void* p = ws + offs;
        offs += (bytes + 255) & ~(size_t)255;
        return p;
    };
    float*    h_tan    = (float*)alloc((size_t)N * 16 * 4);
    float*    loop_hyp = (float*)alloc((size_t)N * 16 * 4);
    float*    ynorm    = (float*)alloc((size_t)N * 4);
    unsigned* bucket   = (unsigned*)alloc((size_t)N * CAP * 4);
    int*      cursor   = (int*)alloc((size_t)N * 4);
    unsigned* wpack    = (unsigned*)alloc((size_t)R * 128 * 4);
    int nZero4 = (N + 3) >> 2;
    int nPack  = R * 64;

    const int threads = 256;
    int blocksZP = (nZero4 + nPack + threads - 1) / threads;
    int blocksN4 = (N * 4 + threads - 1) / threads;
    int blocksE1 = (E + threads - 1) / threads;
    int blocksR  = 2048;                                   // grid-stride over nodes

    fhnn_zero_pack<<<blocksZP, threads, 0, stream>>>(cursor, nZero4, rel_weight, wpack, nPack);
    fhnn_prepscatter<<<blocksN4 + blocksE1, threads, 0, stream>>>(
        h_hyper, loop_weight, src, dst, etype, h_tan, loop_hyp, ynorm, cursor, bucket,
        N, E, blocksN4);
    fhnn_reduce<<<blocksR, threads, 0, stream>>>(
        h_tan, wpack, rel_emb, bucket, cursor, node_norm, loop_hyp, ynorm,
        (float*)d_out, N);
}

// Round 20
// 63.207 us; speedup vs baseline: 1.0752x; 1.0752x over previous
//
#include <hip/hip_runtime.h>

#define C_CURV   0.01f
#define SQRT_C   0.1f
#define EPS_W    1e-6f
#define MIN_NORM 1e-10f
#define BALL_EPS 1e-5f
#define CAP      32    // bucket row = 128B; P(deg>=32 | Poisson(8)) ~ 1e-11
#define WSTRIDE  130   // u32 stride per relation row in LDS

typedef __attribute__((ext_vector_type(4))) float f32x4;

__device__ __forceinline__ float fast_rcp(float x)   { return __builtin_amdgcn_rcpf(x); }
__device__ __forceinline__ float fast_sqrt(float x)  { return __builtin_amdgcn_sqrtf(x); }
__device__ __forceinline__ float fast_rsqrt(float x) { return __builtin_amdgcn_rsqf(x); }
__device__ __forceinline__ float tanh_over_x(float x) {   // tanh(x)/x, x>0
    float t = __expf(2.0f * x);
    return (t - 1.0f) * fast_rcp((t + 1.0f) * x);
}
__device__ __forceinline__ unsigned bf16_rne(float x) {
    unsigned u = __float_as_uint(x);
    return (u + 0x7FFFu + ((u >> 16) & 1u)) >> 16;
}
__device__ __forceinline__ float group4_sum(float v) {   // sum over aligned 4-lane quad
    v += __shfl_xor(v, 1, 64);
    v += __shfl_xor(v, 2, 64);
    return v;
}

// K0: zero cursor[N] (must complete before scatter atomics).
__global__ __launch_bounds__(256) void fhnn_zero(int* __restrict__ cursor, int n4) {
    int i = blockIdx.x * blockDim.x + threadIdx.x;
    if (i < n4) ((int4*)cursor)[i] = make_int4(0, 0, 0, 0);
}

// K1 (fused, disjoint block ranges): node pre-pass (4 lanes/node) + edge scatter.
__global__ __launch_bounds__(256) void fhnn_prepscatter(
        const float* __restrict__ h_hyper,
        const float* __restrict__ loop_weight,
        const int*   __restrict__ src,
        const int*   __restrict__ dst,
        const int*   __restrict__ etype,
        float* __restrict__ h_tan,
        float* __restrict__ loop_hyp,
        float* __restrict__ ynorm,       // [N]: |loop_hyp|^2 precomputed
        int*      __restrict__ cursor,
        unsigned* __restrict__ bucket,   // [N][CAP], word = src | etype<<16
        int N, int E, int blocksN) {
    if ((int)blockIdx.x >= blocksN) {
        int e = (blockIdx.x - blocksN) * blockDim.x + threadIdx.x;
        if (e >= E) return;
        int t = dst[e];
        int slot = atomicAdd(&cursor[t], 1);
        if (slot < CAP)
            bucket[(size_t)t * CAP + slot] = (unsigned)src[e] | ((unsigned)etype[e] << 16);
        return;
    }
    __shared__ float Wl[256];
    Wl[threadIdx.x] = loop_weight[threadIdx.x];
    __syncthreads();

    int gid = blockIdx.x * blockDim.x + threadIdx.x;
    int t = gid >> 2, j = gid & 3;
    if (t >= N) return;

    f32x4 x = ((const f32x4*)h_hyper)[gid];

    float sq  = group4_sum(x.x * x.x + x.y * x.y + x.z * x.z + x.w * x.w);
    float n   = fast_sqrt(fmaxf(sq, MIN_NORM));
    float scn = SQRT_C * n;
    float z   = fminf(scn, 1.0f - BALL_EPS);
    float at  = 0.5f * __logf((1.0f + z) * fast_rcp(1.0f - z));   // arctanh
    float s   = at * fast_rcp(scn);
    f32x4 ht  = x * s;
    ((f32x4*)h_tan)[gid] = ht;

    f32x4 acc = (f32x4)(0.0f);
    #pragma unroll
    for (int q = 0; q < 4; ++q) {
        float h0 = __shfl(ht.x, q, 4);
        float h1 = __shfl(ht.y, q, 4);
        float h2 = __shfl(ht.z, q, 4);
        float h3 = __shfl(ht.w, q, 4);
        const f32x4* Wrow = (const f32x4*)Wl;
        acc += h0 * Wrow[(4 * q + 0) * 4 + j];
        acc += h1 * Wrow[(4 * q + 1) * 4 + j];
        acc += h2 * Wrow[(4 * q + 2) * 4 + j];
        acc += h3 * Wrow[(4 * q + 3) * 4 + j];
    }
    float sq2 = group4_sum(acc.x * acc.x + acc.y * acc.y + acc.z * acc.z + acc.w * acc.w);
    float n2  = fast_sqrt(fmaxf(sq2, MIN_NORM));
    float f2  = tanh_over_x(SQRT_C * n2);           // exp_map_zero factor
    ((f32x4*)loop_hyp)[gid] = acc * f2;
    if (j == 0) ynorm[t] = sq2 * f2 * f2;           // |loop_hyp|^2 for reduce epilogue
}

// Per-edge message + accumulate (WSTEP: bf16x2 LDS read + unpack + fma).
#define WSTEP(HS, I, WSP) { \
    uint2 w = *(const uint2*)((WSP) + 8 * (I)); \
    f32x4 wvv; \
    wvv.x = __uint_as_float(w.x << 16); \
    wvv.y = __uint_as_float(w.x & 0xFFFF0000u); \
    wvv.z = __uint_as_float(w.y << 16); \
    wvv.w = __uint_as_float(w.y & 0xFFFF0000u); \
    a4 += (HS) * wvv; }

#define EDGE(H0, H1, H2, H3, RR, VALID) { \
    const unsigned* Ws = lds_w + (unsigned)(RR) * WSTRIDE + 2u * (unsigned)j; \
    f32x4 a4 = (f32x4)(0.0f); \
    WSTEP((H0).x,  0, Ws) WSTEP((H0).y,  1, Ws) WSTEP((H0).z,  2, Ws) WSTEP((H0).w,  3, Ws) \
    WSTEP((H1).x,  4, Ws) WSTEP((H1).y,  5, Ws) WSTEP((H1).z,  6, Ws) WSTEP((H1).w,  7, Ws) \
    WSTEP((H2).x,  8, Ws) WSTEP((H2).y,  9, Ws) WSTEP((H2).z, 10, Ws) WSTEP((H2).w, 11, Ws) \
    WSTEP((H3).x, 12, Ws) WSTEP((H3).y, 13, Ws) WSTEP((H3).z, 14, Ws) WSTEP((H3).w, 15, Ws) \
    f32x4 v = a4 + *(const f32x4*)(relE + (RR) * 16 + 4 * j); \
    float sq = group4_sum(v.x * v.x + v.y * v.y + v.z * v.z + v.w * v.w); \
    float f  = tanh_over_x(SQRT_C * fast_sqrt(fmaxf(sq, MIN_NORM))); \
    float m2 = f * f * sq; \
    float lam = 2.0f * fast_rcp(1.0f - C_CURV * m2 + EPS_W); \
    float cf = (VALID) ? (f * lam) : 0.0f; \
    accM += v * cf; \
    accL += (VALID) ? lam : 0.0f; }

// One edge-block: decode pk, gather h row, run EDGE. k-index = slot + 4*blk.
#define EDGEBLK(PK, KIDX) { \
    bool vld = (KIDX) < cn; \
    int s = vld ? (int)((PK) & 0xFFFFu) : 0; \
    int r = vld ? (int)((PK) >> 16) : 0; \
    const f32x4* H = (const f32x4*)(h_tan + (size_t)s * 16); \
    f32x4 q0 = H[0], q1 = H[1], q2 = H[2], q3 = H[3]; \
    EDGE(q0, q1, q2, q3, r, vld) }

// K2: reduce. STRIDED slot->k map (k = slot + 4*blk) so each edge-block is
// wave-uniformly skippable via __any(cn > 4*blk): Poisson(8) degrees skip
// block 3 ~77%, block 2 ~12% of waves. LDS bf16 W (L0-latency W reads beat
// the occupancy cost of 134KB LDS — R18 A/B confirmed).
__global__ __launch_bounds__(1024, 1) void fhnn_reduce(
        const float*    __restrict__ h_tan,
        const float*    __restrict__ rel_weight,
        const float*    __restrict__ rel_emb,
        const unsigned* __restrict__ bucket,
        const int*      __restrict__ cursor,
        const float*    __restrict__ node_norm,
        const float*    __restrict__ loop_hyp,
        const float*    __restrict__ ynorm,
        float*          __restrict__ out,
        int N, int R) {
    extern __shared__ unsigned lds_w[];
    const int relOff = ((R * WSTRIDE + 3) & ~3);
    float* relE = (float*)(lds_w + relOff);

    for (int idx = threadIdx.x; idx < R * 64; idx += blockDim.x) {
        int r = idx >> 6, c4 = idx & 63;
        f32x4 w = ((const f32x4*)rel_weight)[idx];
        lds_w[r * WSTRIDE + 2 * c4]     = bf16_rne(w.x) | (bf16_rne(w.y) << 16);
        lds_w[r * WSTRIDE + 2 * c4 + 1] = bf16_rne(w.z) | (bf16_rne(w.w) << 16);
    }
    for (int idx = threadIdx.x; idx < R * 16; idx += blockDim.x)
        relE[idx] = rel_emb[idx];
    __syncthreads();

    int wv   = threadIdx.x >> 6;
    int lane = threadIdx.x & 63;
    int grp  = lane >> 4;
    int slot = (lane >> 2) & 3;
    int j    = lane & 3;
    int wstart  = (blockIdx.x * 16 + wv) * 4 + grp;
    int nstride = gridDim.x * 16 * 4;

    // prime: first node-group's cursor + first bucket word
    int cnF = 0;
    unsigned pk0 = 0u;
    if (wstart < N) {
        cnF = cursor[wstart];
        pk0 = bucket[(size_t)wstart * CAP + slot];
    }

    for (int t = wstart; t < N; t += nstride) {
        // prefetch NEXT node-group (hides cursor/bucket first-chain latency)
        int tn = t + nstride;
        int cnF_n = 0;
        unsigned pk0_n = 0u;
        if (tn < N) {
            cnF_n = cursor[tn];
            pk0_n = bucket[(size_t)tn * CAP + slot];
        }

        int cnFull = cnF;
        int cn = min(cnFull, CAP);
        size_t bbase = (size_t)t * CAP + slot;

        // remaining bucket words (same 128B line as pk0 -> L1-hot)
        unsigned pk1 = bucket[bbase + 4];
        unsigned pk2 = bucket[bbase + 8];
        unsigned pk3 = bucket[bbase + 12];

        // epilogue operands, issued early
        float en = node_norm[t];
        f32x4 y  = ((const f32x4*)(loop_hyp + (size_t)t * 16))[j];
        float y2 = ynorm[t];

        f32x4 accM = (f32x4)(0.0f);
        float accL = 0.0f;

        EDGEBLK(pk0, slot)                                     // k = slot
        if (__any(cn >  4)) EDGEBLK(pk1, slot + 4)             // k = slot+4
        if (__any(cn >  8)) EDGEBLK(pk2, slot + 8)             // k = slot+8
        if (__any(cn > 12)) EDGEBLK(pk3, slot + 12)            // k = slot+12
        if (__any(cn > 16)) {                                  // rare tail (~0.3%)
            for (int k = 16 + slot; k < cn; k += 4) {
                unsigned pk = bucket[(size_t)t * CAP + k];
                int s = (int)(pk & 0xFFFFu);
                int r = (int)(pk >> 16);
                const f32x4* H = (const f32x4*)(h_tan + (size_t)s * 16);
                f32x4 q0 = H[0], q1 = H[1], q2 = H[2], q3 = H[3];
                EDGE(q0, q1, q2, q3, r, true)
            }
        }

        #pragma unroll
        for (int m = 4; m <= 8; m <<= 1) {
            accM.x += __shfl_xor(accM.x, m, 64);
            accM.y += __shfl_xor(accM.y, m, 64);
            accM.z += __shfl_xor(accM.z, m, 64);
            accM.w += __shfl_xor(accM.w, m, 64);
            accL   += __shfl_xor(accL,   m, 64);
        }

        float wsc   = en * fast_rcp((float)cnFull * en + EPS_W);  // norm_sum = deg*en
        float denom = wsc * accL + EPS_W;
        float rs    = wsc * fast_rcp(denom);
        f32x4 x     = accM * rs;

        // project_to_ball: analytic post-norm (saves a group4_sum)
        float x2 = group4_sum(x.x * x.x + x.y * x.y + x.z * x.z + x.w * x.w);
        const float maxn  = (1.0f - BALL_EPS) / SQRT_C;
        const float maxn2 = maxn * maxn;
        bool over = (x2 > maxn2);
        float scale = over ? (maxn * fast_rsqrt(x2)) : 1.0f;
        x *= scale;
        float x2p = over ? maxn2 : x2;

        float xy = group4_sum(x.x * y.x + x.y * y.y + x.z * y.z + x.w * y.w);

        float a1  = 1.0f + 2.0f * C_CURV * xy + C_CURV * y2;
        float b1  = 1.0f - C_CURV * x2p;
        f32x4 num = a1 * x + b1 * y;
        float d2  = 1.0f + 2.0f * C_CURV * xy + C_CURV * C_CURV * x2p * y2;
        if (slot == 0)
            ((f32x4*)out)[t * 4 + j] = num * fast_rcp(fmaxf(d2, MIN_NORM));

        cnF = cnF_n;
        pk0 = pk0_n;
    }
}

extern "C" void kernel_launch(void* const* d_in, const int* in_sizes, int n_in,
                              void* d_out, int out_size, void* d_ws, size_t ws_size,
                              hipStream_t stream) {
    const float* h_hyper     = (const float*)d_in[0];
    const float* node_norm   = (const float*)d_in[1];
    const float* rel_weight  = (const float*)d_in[2];
    const float* loop_weight = (const float*)d_in[3];
    const float* rel_emb     = (const float*)d_in[4];
    const int*   src         = (const int*)d_in[5];
    const int*   dst         = (const int*)d_in[6];
    const int*   etype       = (const int*)d_in[7];

    const int N = in_sizes[1];          // node_norm is [N,1]
    const int E = in_sizes[5];
    const int R = in_sizes[2] / 256;    // rel_weight is [R,16,16]

    char* ws = (char*)d_ws;
    size_t offs = 0;
    auto alloc = [&](size_t bytes) -> void* {
        void* p = ws + offs;
        offs += (bytes + 255) & ~(size_t)255;
        return p;
    };
    float*    h_tan    = (float*)alloc((size_t)N * 16 * 4);
    float*    loop_hyp = (float*)alloc((size_t)N * 16 * 4);
    float*    ynorm    = (float*)alloc((size_t)N * 4);
    unsigned* bucket   = (unsigned*)alloc((size_t)N * CAP * 4);
    int*      cursor   = (int*)alloc((size_t)N * 4);
    int nZero4 = (N + 3) >> 2;

    int relOff   = ((R * WSTRIDE + 3) & ~3);
    int ldsBytes = (relOff + R * 16) * 4;
    hipFuncSetAttribute((const void*)fhnn_reduce,
                        hipFuncAttributeMaxDynamicSharedMemorySize, ldsBytes);

    const int threads = 256;
    int blocksZ  = (nZero4 + threads - 1) / threads;
    int blocksN4 = (N * 4 + threads - 1) / threads;
    int blocksE1 = (E + threads - 1) / threads;

    fhnn_zero<<<blocksZ, threads, 0, stream>>>(cursor, nZero4);
    fhnn_prepscatter<<<blocksN4 + blocksE1, threads, 0, stream>>>(
        h_hyper, loop_weight, src, dst, etype, h_tan, loop_hyp, ynorm, cursor, bucket,
        N, E, blocksN4);
    fhnn_reduce<<<256, 1024, ldsBytes, stream>>>(
        h_tan, rel_weight, rel_emb, bucket, cursor, node_norm, loop_hyp, ynorm,
        (float*)d_out, N, R);
}